// Round 7
// baseline (343.993 us; speedup 1.0000x reference)
//
#include <hip/hip_runtime.h>
#include <cstdint>
#include <cstddef>

// PositionalEncoderGrid: Instant-NGP multiresolution hash grid.
// B=524288 points, L=16 levels, T=2^19 entries/level, F=2 floats.
//
// R14: R13 with phase A merged into ONE dispatch. Evidence ledger:
//      - gather service = ~3.1 cyc per ACTIVE-LANE request per CU, invariant
//        to L2 residency up to ~2 tables/XCD (R7/R8/R10), degrades ~40% only
//        when fully unpinned (R12, FETCH 949MB).
//      - x-pair trick floor: 6 req/pt/level (only x has XOR-bit-0 hash
//        structure; y/z primes are odd -> no further pairing).
//      - fixed harness overhead ~72us, independent of dispatch count.
//      Merged schedule: 14 levels (l2-15) x 2048 chunks, level-major per
//      XCD slot (3584 chunks = 1.75 levels/XCD, <=2 tables sequential --
//      the rate-safe regime). Kills the pass1/pass2 gap + one tail.
//      l0/l1 stay fused in the transpose (R13, verified).

#define NUM_LEVELS 16
#define TBL_MASK ((1u << 19) - 1u)
#define PRIME_Y 2654435761u
#define PRIME_Z 805459861u
#define BATCH 524288

typedef float nfloat4 __attribute__((ext_vector_type(4)));
typedef double ndouble2 __attribute__((ext_vector_type(2)));

__constant__ float c_ns[NUM_LEVELS] = {
    16.f, 20.f, 25.f, 32.f, 40.f, 50.f, 64.f, 80.f,
    101.f, 128.f, 161.f, 203.f, 256.f, 322.f, 406.f, 512.f
};

__device__ __forceinline__ float2 d2f2(double d) {
    union { double d; float2 f; } u;
    u.d = d;
    return u.f;
}

__device__ __forceinline__ double f22d(float2 f) {
    union { double d; float2 f; } u;
    u.f = f;
    return u.d;
}

// chunk-major ws index (float2/double units): [p>>8][l][p&255]
__device__ __forceinline__ size_t ws_idx(int p, int l) {
    return ((size_t)(p >> 8) * NUM_LEVELS + l) * 256 + (p & 255);
}

// One level's trilinear hash-grid lookup for one point (verified R10/R12).
// x-pair trick: corners (x0,c),(x1,c) satisfy i_x1 == i_x0 ^ 1 when px even;
// {i&~1, i|1} is one aligned 16B pair -> one dwordx4 covers both corners.
// Odd-px lanes issue 4 extra exec-masked gathers. Avg 6 req/pt/level.
__device__ __forceinline__ float2 level_eval(
    int l, float xs, float ys, float zs,
    const double* __restrict__ table_d)
{
    const float n = c_ns[l];
    const float tx = xs * n, ty = ys * n, tz = zs * n;
    const float fpx = floorf(tx), fpy = floorf(ty), fpz = floorf(tz);
    const float wx1 = tx - fpx, wy1 = ty - fpy, wz1 = tz - fpz;
    const uint32_t px = (uint32_t)fpx;
    const uint32_t py = (uint32_t)fpy;
    const uint32_t pz = (uint32_t)fpz;

    const uint32_t hy0 = py * PRIME_Y, hy1 = hy0 + PRIME_Y;
    const uint32_t hz0 = pz * PRIME_Z, hz1 = hz0 + PRIME_Z;
    const uint32_t b0 = hy0 ^ hz0, b1 = hy0 ^ hz1;
    const uint32_t b2 = hy1 ^ hz0, b3 = hy1 ^ hz1;

    const uint32_t i00 = (px ^ b0) & TBL_MASK;
    const uint32_t i01 = (px ^ b1) & TBL_MASK;
    const uint32_t i02 = (px ^ b2) & TBL_MASK;
    const uint32_t i03 = (px ^ b3) & TBL_MASK;
    const uint32_t qx = px + 1u;
    const uint32_t i40 = (qx ^ b0) & TBL_MASK;
    const uint32_t i41 = (qx ^ b1) & TBL_MASK;
    const uint32_t i42 = (qx ^ b2) & TBL_MASK;
    const uint32_t i43 = (qx ^ b3) & TBL_MASK;

    const double* __restrict__ tb = table_d + ((size_t)l << 19);
    const ndouble2* __restrict__ tb2 = (const ndouble2*)tb;

    const ndouble2 q0 = tb2[i00 >> 1];
    const ndouble2 q1 = tb2[i01 >> 1];
    const ndouble2 q2 = tb2[i02 >> 1];
    const ndouble2 q3 = tb2[i03 >> 1];

    const bool odd = (px & 1u) != 0u;
    double g0 = 0.0, g1 = 0.0, g2 = 0.0, g3 = 0.0;
    if (odd) {   // exec-masked: only odd-px lanes issue these 4 gathers
        g0 = tb[i40];
        g1 = tb[i41];
        g2 = tb[i42];
        g3 = tb[i43];
    }

    const double e00 = (i00 & 1u) ? q0.y : q0.x;
    const double e01 = (i01 & 1u) ? q1.y : q1.x;
    const double e02 = (i02 & 1u) ? q2.y : q2.x;
    const double e03 = (i03 & 1u) ? q3.y : q3.x;
    const double p00 = (i00 & 1u) ? q0.x : q0.y;
    const double p01 = (i01 & 1u) ? q1.x : q1.y;
    const double p02 = (i02 & 1u) ? q2.x : q2.y;
    const double p03 = (i03 & 1u) ? q3.x : q3.y;

    float2 f[8];
    f[0] = d2f2(e00); f[1] = d2f2(e01); f[2] = d2f2(e02); f[3] = d2f2(e03);
    f[4] = d2f2(odd ? g0 : p00);
    f[5] = d2f2(odd ? g1 : p01);
    f[6] = d2f2(odd ? g2 : p02);
    f[7] = d2f2(odd ? g3 : p03);

    const float wx0 = 1.0f - wx1;
    const float wy0 = 1.0f - wy1;
    const float wz0 = 1.0f - wz1;

    float a0 = 0.0f, a1 = 0.0f, w;
    w = wx0 * wy0 * wz0; a0 = fmaf(f[0].x, w, a0); a1 = fmaf(f[0].y, w, a1);
    w = wx0 * wy0 * wz1; a0 = fmaf(f[1].x, w, a0); a1 = fmaf(f[1].y, w, a1);
    w = wx0 * wy1 * wz0; a0 = fmaf(f[2].x, w, a0); a1 = fmaf(f[2].y, w, a1);
    w = wx0 * wy1 * wz1; a0 = fmaf(f[3].x, w, a0); a1 = fmaf(f[3].y, w, a1);
    w = wx1 * wy0 * wz0; a0 = fmaf(f[4].x, w, a0); a1 = fmaf(f[4].y, w, a1);
    w = wx1 * wy0 * wz1; a0 = fmaf(f[5].x, w, a0); a1 = fmaf(f[5].y, w, a1);
    w = wx1 * wy1 * wz0; a0 = fmaf(f[6].x, w, a0); a1 = fmaf(f[6].y, w, a1);
    w = wx1 * wy1 * wz1; a0 = fmaf(f[7].x, w, a0); a1 = fmaf(f[7].y, w, a1);
    return make_float2(a0, a1);
}

// Phase A, merged: 14 levels (l2..15), level-major contiguous per XCD slot.
// g = slot*3584 + seq; level = 2 + g/2048; chunk-in-level = g%2048.
// Each XCD walks 1.75 levels sequentially -> <=2 tables, one at a time.
__global__ __launch_bounds__(256) void enc_sched_kernel(
    const float* __restrict__ in,
    const float* __restrict__ table,
    double* __restrict__ ws)
{
    const int slot = blockIdx.x & 7;           // -> XCD
    const int seq  = blockIdx.x >> 3;
    const int g = slot * 3584 + seq;           // 14 * 2048 / 8 = 3584
    const int l = 2 + (g >> 11);               // 2048 chunks per level
    const int cil = g & 2047;
    const int p = cil * 256 + threadIdx.x;

    // Streaming input: nt so it doesn't evict the L2-resident table.
    const float vx = __builtin_nontemporal_load(&in[p * 3 + 0]);
    const float vy = __builtin_nontemporal_load(&in[p * 3 + 1]);
    const float vz = __builtin_nontemporal_load(&in[p * 3 + 2]);
    const float xs = (vx + 3.0f) / 6.0f;
    const float ys = (vy + 3.0f) / 6.0f;
    const float zs = (vz + 3.0f) / 6.0f;

    const float2 r = level_eval(l, xs, ys, zs, (const double*)table);

    __builtin_nontemporal_store(f22d(r), &ws[ws_idx(p, l)]);
}

// Phase B fused: per-chunk transpose of l2..15 from ws + INLINE l0/l1 eval
// (12 req/pt; tables 0.3+0.6MB -> L2-hot on every XCD), then 256x128B
// coalesced output writes. (Verified R13.)
__global__ __launch_bounds__(256) void transpose_coarse_kernel(
    const float* __restrict__ in,
    const double* __restrict__ ws,
    const float* __restrict__ table,
    nfloat4* __restrict__ out)                 // [B*8]
{
    __shared__ double lds[256][NUM_LEVELS + 1];   // +1 pad

    const int tid = threadIdx.x;
    const int p = blockIdx.x * 256 + tid;
    const size_t base = (size_t)blockIdx.x * (NUM_LEVELS * 256);

    // Stage fine levels from ws (contiguous 2KB per level slot).
#pragma unroll
    for (int l = 2; l < NUM_LEVELS; ++l) {
        lds[tid][l] = __builtin_nontemporal_load(&ws[base + (size_t)l * 256 + tid]);
    }

    // Inline coarse levels: coalesced coord load, cached table gathers.
    const float vx = in[p * 3 + 0];
    const float vy = in[p * 3 + 1];
    const float vz = in[p * 3 + 2];
    const float xs = (vx + 3.0f) / 6.0f;
    const float ys = (vy + 3.0f) / 6.0f;
    const float zs = (vz + 3.0f) / 6.0f;
    const double* __restrict__ table_d = (const double*)table;
    lds[tid][0] = f22d(level_eval(0, xs, ys, zs, table_d));
    lds[tid][1] = f22d(level_eval(1, xs, ys, zs, table_d));

    __syncthreads();

    // 2048 float4s per block; lane-contiguous stores.
#pragma unroll
    for (int it = 0; it < 8; ++it) {
        const int e = it * 256 + tid;
        const int pp = e >> 3;         // point within tile
        const int j = e & 7;           // float4 index within point
        const float2 a = d2f2(lds[pp][2 * j]);
        const float2 b = d2f2(lds[pp][2 * j + 1]);
        nfloat4 r;
        r.x = a.x; r.y = a.y; r.z = b.x; r.w = b.y;
        __builtin_nontemporal_store(r, &out[(size_t)blockIdx.x * 2048 + e]);
    }
}

// Fallback: direct scatter store (no workspace needed).
__global__ __launch_bounds__(256) void enc_scatter_kernel(
    const float* __restrict__ in,
    const float* __restrict__ table,
    float2* __restrict__ out)          // [B, 16] float2
{
    const int v = blockIdx.x & 15;
    const int chunk = blockIdx.x >> 4;
    const int l = (v < 8) ? (15 - v) : (v - 8);
    const int p = chunk * 256 + threadIdx.x;

    const float vx = in[p * 3 + 0];
    const float vy = in[p * 3 + 1];
    const float vz = in[p * 3 + 2];
    const float2 r = level_eval(l, (vx + 3.0f) / 6.0f, (vy + 3.0f) / 6.0f,
                                (vz + 3.0f) / 6.0f, (const double*)table);
    out[(size_t)p * NUM_LEVELS + l] = r;
}

extern "C" void kernel_launch(void* const* d_in, const int* in_sizes, int n_in,
                              void* d_out, int out_size, void* d_ws, size_t ws_size,
                              hipStream_t stream) {
    const float* inputs = (const float*)d_in[0];   // [B,3] fp32
    const float* table  = (const float*)d_in[1];   // [16, 2^19, 2] fp32

    const size_t ws_needed = (size_t)NUM_LEVELS * BATCH * sizeof(float2); // 64 MiB

    if (ws_size >= ws_needed) {
        double* ws = (double*)d_ws;
        // Phase A merged: l2..15, 14 * 2048 = 28672 blocks.
        enc_sched_kernel<<<28672, 256, 0, stream>>>(inputs, table, ws);
        // Phase B: fused transpose + inline l0/l1 (2048 blocks).
        transpose_coarse_kernel<<<2048, 256, 0, stream>>>(
            inputs, ws, table, (nfloat4*)d_out);
    } else {
        enc_scatter_kernel<<<32768, 256, 0, stream>>>(inputs, table, (float2*)d_out);
    }
}